// Round 3
// baseline (2185.730 us; speedup 1.0000x reference)
//
#include <hip/hip_runtime.h>
#include <cfloat>

// Problem constants: B=16, N=8192, C=256; M derived from out_size (=2048).
// R3 == R2 intent with the transpose OOB bug fixed (TIT was 2048/NT, must be
// 1024/NT float4-iterations per 64x64 tile). FPS: NT 512->1024, PPT 16->8 ->
// 4 waves/SIMD so the per-wave serial chain (LDS round trips + DPP reduce) is
// 4-way overlapped per SIMD instead of 2-way. Total issue per iter unchanged.
#define BB 16
#define NN 8192
#define CC 256
#define NT 1024                 // threads per FPS block (16 waves)
#define PPT 8                   // points per thread
#define NPAIR (PPT / 2)         // 4 packed f32x2 pairs
#define NWAVES (NT / 64)        // 16
#define TIT (1024 / NT)         // transpose float4 iters per tile (=1)
#define TBLOCKS 240             // transpose helper blocks (fill idle CUs)
#define NTILES (BB * (CC / 64) * (NN / 64))   // 16*4*128 = 8192 64x64 tiles

typedef float    v2f __attribute__((ext_vector_type(2)));
typedef unsigned v2u __attribute__((ext_vector_type(2)));
typedef unsigned uu;
typedef unsigned long long ull;

// Barrier that waits ONLY on LDS (lgkmcnt), not vmcnt. __syncthreads emits
// "s_waitcnt vmcnt(0) lgkmcnt(0); s_barrier" — the vmcnt(0) forces wave 0 to
// wait for its per-iteration global stores (idx/out_pts) to RETIRE before the
// barrier. Our only cross-wave data is the LDS key write -> lgkmcnt(0)
// suffices; global stores are drained at s_endpgm.
#define LDS_BARRIER() __asm__ __volatile__("s_waitcnt lgkmcnt(0)\n\ts_barrier" ::: "memory")

// Shared memory. FPS view: separate x/y/z coord arrays -> winner-coord fetch
// is 3x b32 same-address broadcast (conflict-free). Union with the transpose
// tile so both paths fit one ~98.5 KB block (1 block/CU each).
// NOTE (R0 measured): SQ_LDS_BANK_CONFLICT == 2^21 comes from the transpose
// tile's 2-way aliasing (benign per m136), NOT from the FPS path.
struct SmemFPS {
  float px[NN], py[NN], pz[NN];           // 96 KB point mirror
  ull   key[2][NWAVES];                   // double-buffered wave keys
  float red[NWAVES][3];
  float ctr[3];
};
struct SmemT {
  float tile[64][65];                     // padded transpose tile
};
union Smem { SmemFPS f; SmemT t; };

// ---- guaranteed-packed f32 math (VOP3P). Each half is a plain IEEE f32 op
// (round-to-nearest-even), bit-identical to the scalar version. ----
__device__ __forceinline__ v2f pk_sub(v2f a, v2f b) {
  v2f d;
  asm("v_pk_add_f32 %0, %1, %2 neg_lo:[0,1] neg_hi:[0,1]"
      : "=v"(d) : "v"(a), "v"(b));
  return d;
}
__device__ __forceinline__ v2f pk_mul(v2f a, v2f b) {
  v2f d;
  asm("v_pk_mul_f32 %0, %1, %2" : "=v"(d) : "v"(a), "v"(b));
  return d;
}
__device__ __forceinline__ v2f pk_add(v2f a, v2f b) {
  v2f d;
  asm("v_pk_add_f32 %0, %1, %2" : "=v"(d) : "v"(a), "v"(b));
  return d;
}

__device__ __forceinline__ uu umin2(uu a, uu b) { return a < b ? a : b; }
__device__ __forceinline__ uu umax2(uu a, uu b) { return a > b ? a : b; }

// key = (dist_bits << 32) | ~index. dist >= 0 -> u32 bit order == f32 order.
// max key = max dist; tie -> larger ~idx = smaller idx = numpy first-occurrence.
__device__ __forceinline__ ull max64(ull a, ull b) { return a > b ? a : b; }

// One DPP max step on a u64 key (both 32-bit halves move with same pattern).
template <int CTRL>
__device__ __forceinline__ ull dpp_max64(ull x) {
  int lo = (int)(uu)x;
  int hi = (int)(uu)(x >> 32);
  int plo = __builtin_amdgcn_update_dpp(0, lo, CTRL, 0xF, 0xF, true);
  int phi = __builtin_amdgcn_update_dpp(0, hi, CTRL, 0xF, 0xF, true);
  ull p = ((ull)(uu)phi << 32) | (uu)plo;
  return max64(x, p);
}

// Wave64 max funneled into lane 63, all on the VALU pipe (no LDS-pipe ops).
__device__ __forceinline__ ull wave_max63(ull k) {
  k = dpp_max64<0xB1>(k);    // quad_perm xor1
  k = dpp_max64<0x4E>(k);    // quad_perm xor2
  k = dpp_max64<0x124>(k);   // row_ror:4
  k = dpp_max64<0x128>(k);   // row_ror:8 -> full 16-lane row max
  k = dpp_max64<0x142>(k);   // row_bcast15
  k = dpp_max64<0x143>(k);   // row_bcast31 -> lane 63 has wave max
  return k;
}

// blockIdx < BB: one FPS workgroup per batch.
// blockIdx >= BB (when do_trans): grid-stride transpose of features
// [B][C][N] -> trans [B][N][C], hidden under FPS on the idle 240 CUs.
__global__ __launch_bounds__(NT)
void fps_fused_kernel(const float* __restrict__ pts,
                      const float* __restrict__ feats,
                      float* __restrict__ out_pts,
                      int* __restrict__ idx_out,
                      float* __restrict__ trans, int M, int do_trans) {
  __shared__ Smem sm;
  const int t = threadIdx.x;

  if (blockIdx.x >= BB) {
    // ---------------- transpose path ----------------
    if (!do_trans) return;
    for (int tileId = blockIdx.x - BB; tileId < NTILES; tileId += TBLOCKS) {
      int b  = tileId / ((CC / 64) * (NN / 64));
      int r  = tileId % ((CC / 64) * (NN / 64));
      int ct = r / (NN / 64);           // c-tile 0..3
      int nt = r % (NN / 64);           // n-tile 0..127
      const float* src = feats + ((size_t)b * CC + ct * 64) * NN + nt * 64;
      float* dst = trans + ((size_t)b * NN + nt * 64) * CC + ct * 64;
#pragma unroll
      for (int i = 0; i < TIT; ++i) {   // 1024 float4 loads total per tile
        int f = t + i * NT;             // NT=1024 -> f == t, one pass
        int c = f >> 4, n4 = f & 15;
        float4 v = *(const float4*)(src + (size_t)c * NN + n4 * 4);
        sm.t.tile[c][n4 * 4 + 0] = v.x;
        sm.t.tile[c][n4 * 4 + 1] = v.y;
        sm.t.tile[c][n4 * 4 + 2] = v.z;
        sm.t.tile[c][n4 * 4 + 3] = v.w;
      }
      __syncthreads();
#pragma unroll
      for (int i = 0; i < TIT; ++i) {
        int f = t + i * NT;
        int n = f >> 4, c4 = f & 15;
        float4 o;
        o.x = sm.t.tile[c4 * 4 + 0][n];
        o.y = sm.t.tile[c4 * 4 + 1][n];
        o.z = sm.t.tile[c4 * 4 + 2][n];
        o.w = sm.t.tile[c4 * 4 + 3][n];
        *(float4*)(dst + (size_t)n * CC + c4 * 4) = o;
      }
      __syncthreads();                  // tile reuse across grid-stride iters
    }
    return;
  }

  // ---------------- FPS path ----------------
  const int b = blockIdx.x;
  const int wave = t >> 6;
  const int lane = t & 63;
  const float* base = pts + (size_t)b * 3 * NN;   // [3][N] for this batch

  v2f px2[NPAIR], py2[NPAIR], pz2[NPAIR];
  v2u dist2[NPAIR];
  const uu INIT = __float_as_uint(1e10f);         // matches jnp.full(1e10)
#pragma unroll
  for (int j = 0; j < NPAIR; ++j) {
    int n0 = t + (2 * j) * NT;                    // coalesced loads
    int n1 = t + (2 * j + 1) * NT;
    float x0 = base[n0], y0 = base[NN + n0], z0 = base[2 * NN + n0];
    float x1 = base[n1], y1 = base[NN + n1], z1 = base[2 * NN + n1];
    px2[j] = (v2f){x0, x1};
    py2[j] = (v2f){y0, y1};
    pz2[j] = (v2f){z0, z1};
    sm.f.px[n0] = x0; sm.f.py[n0] = y0; sm.f.pz[n0] = z0;
    sm.f.px[n1] = x1; sm.f.py[n1] = y1; sm.f.pz[n1] = z1;
    dist2[j] = (v2u){INIT, INIT};
  }

  // ---- centroid (one-time; latency irrelevant; standard barriers OK) ----
  float sx = 0.f, sy = 0.f, sz = 0.f;
#pragma unroll
  for (int j = 0; j < NPAIR; ++j) {
    sx += px2[j].x; sx += px2[j].y;
    sy += py2[j].x; sy += py2[j].y;
    sz += pz2[j].x; sz += pz2[j].y;
  }
#pragma unroll
  for (int off = 32; off > 0; off >>= 1) {
    sx += __shfl_xor(sx, off);
    sy += __shfl_xor(sy, off);
    sz += __shfl_xor(sz, off);
  }
  if (lane == 0) { sm.f.red[wave][0] = sx; sm.f.red[wave][1] = sy; sm.f.red[wave][2] = sz; }
  __syncthreads();    // also covers coord-mirror staging writes
  if (t == 0) {
    float gx = 0.f, gy = 0.f, gz = 0.f;
    for (int w = 0; w < NWAVES; ++w) { gx += sm.f.red[w][0]; gy += sm.f.red[w][1]; gz += sm.f.red[w][2]; }
    sm.f.ctr[0] = gx / NN; sm.f.ctr[1] = gy / NN; sm.f.ctr[2] = gz / NN;  // /8192 exact
  }
  __syncthreads();
  const float ctx = sm.f.ctr[0], cty = sm.f.ctr[1], ctz = sm.f.ctr[2];

  int ep = 0;   // key epoch (parity double-buffer -> one barrier per iter)
  int ci;

  // Tail: u64 key wave reduce via DPP (VALU only), lane-63 write, ONE
  // lgkm-only barrier, then a spread b64 read (lane reads key[lane&15];
  // conflict-free 2-way aliasing) + 4 DPP steps so every lane holds the
  // block max over the 16 wave keys.
  auto reduce_tail = [&](uu v, int bk) {
    ull key = ((ull)v << 32) | (uu)(~(uu)(t + bk * NT));
    key = wave_max63(key);
    ep ^= 1;
    if (lane == 63) sm.f.key[ep][wave] = key;
    LDS_BARRIER();                      // lgkmcnt-only: no global-store drain
    ull kk = sm.f.key[ep][lane & 15];   // spread ds_read_b64
    kk = dpp_max64<0xB1>(kk);           // xor1 within 16-key group
    kk = dpp_max64<0x4E>(kk);           // xor2
    kk = dpp_max64<0x124>(kk);          // row_ror:4
    kk = dpp_max64<0x128>(kk);          // row_ror:8 -> completes all-16 max
    ci = (int)~(uu)kk;
  };

  // ---- initial farthest = argmax of dist-to-centroid (no dist update) ----
  {
    v2f c2x = {ctx, ctx}, c2y = {cty, cty}, c2z = {ctz, ctz};
    v2u nd2[NPAIR];
    uu v = 0u;
#pragma unroll
    for (int j = 0; j < NPAIR; ++j) {
      v2f dx = pk_sub(px2[j], c2x);
      v2f dy = pk_sub(py2[j], c2y);
      v2f dz = pk_sub(pz2[j], c2z);
      // exact numpy order: ((dx*dx + dy*dy) + dz*dz), no FMA
      v2f d = pk_add(pk_add(pk_mul(dx, dx), pk_mul(dy, dy)), pk_mul(dz, dz));
      v2u du = (v2u){__float_as_uint(d.x), __float_as_uint(d.y)};
      nd2[j] = du;
      v = umax2(v, umax2(du.x, du.y));           // v_max3_u32
    }
    int bk = 0;
#pragma unroll
    for (int k = PPT - 1; k >= 0; --k) {         // descending: keeps smallest k
      uu ndk = (k & 1) ? nd2[k >> 1].y : nd2[k >> 1].x;
      if (ndk == v) bk = k;                      // first-occurrence tie-break
    }
    reduce_tail(v, bk);
  }

  // ---- FPS main loop ----
  for (int m = 0; m < M; ++m) {
    // winner coords: 3x b32 same-address broadcast (conflict-free)
    float cx = sm.f.px[ci], cy = sm.f.py[ci], cz = sm.f.pz[ci];
    if (t == 0) {
      idx_out[b * M + m] = ci;
      size_t o = ((size_t)b * M + m) * 3;
      out_pts[o] = cx; out_pts[o + 1] = cy; out_pts[o + 2] = cz;
    }
    if (m == M - 1) break;

    v2f c2x = {cx, cx}, c2y = {cy, cy}, c2z = {cz, cz};
    v2u nd2[NPAIR];
    uu v = 0u;
#pragma unroll
    for (int j = 0; j < NPAIR; ++j) {
      v2f dx = pk_sub(px2[j], c2x);
      v2f dy = pk_sub(py2[j], c2y);
      v2f dz = pk_sub(pz2[j], c2z);
      v2f d = pk_add(pk_add(pk_mul(dx, dx), pk_mul(dy, dy)), pk_mul(dz, dz));
      // dists >= 0 -> u32 min/max on the bits == f32 min/max
      v2u nd;
      nd.x = umin2(dist2[j].x, __float_as_uint(d.x));
      nd.y = umin2(dist2[j].y, __float_as_uint(d.y));
      dist2[j] = nd;
      nd2[j] = nd;
      v = umax2(v, umax2(nd.x, nd.y));           // v_max3_u32 chain
    }
    int bk = 0;
#pragma unroll
    for (int k = PPT - 1; k >= 0; --k) {
      uu ndk = (k & 1) ? nd2[k >> 1].y : nd2[k >> 1].x;
      if (ndk == v) bk = k;
    }
    reduce_tail(v, bk);
  }
}

// Gather from transposed features: fully coalesced float4 both sides.
__global__ __launch_bounds__(256)
void gather_t_kernel(const float* __restrict__ trans,
                     const int* __restrict__ idx,
                     float* __restrict__ out_f, int M) {
  int gm = blockIdx.x * 4 + (threadIdx.x >> 6);
  if (gm >= BB * M) return;
  int lane = threadIdx.x & 63;
  int b = gm / M;
  int n = idx[gm];
  float4 v = *(const float4*)(trans + ((size_t)b * NN + n) * CC + lane * 4);
  *(float4*)(out_f + (size_t)gm * CC + lane * 4) = v;
}

// Fallback gather (ws too small for transpose): scattered reads, L2/L3-bound.
__global__ __launch_bounds__(CC)
void gather_kernel(const float* __restrict__ feats, const int* __restrict__ idx,
                   float* __restrict__ out_f, int M) {
  const int bm = blockIdx.x;
  const int b = bm / M;
  const int n = idx[bm];
  const int c = threadIdx.x;
  out_f[(size_t)bm * CC + c] = feats[((size_t)b * CC + c) * NN + n];
}

extern "C" void kernel_launch(void* const* d_in, const int* in_sizes, int n_in,
                              void* d_out, int out_size, void* d_ws, size_t ws_size,
                              hipStream_t stream) {
  const float* points = (const float*)d_in[0];   // [B,3,N] f32
  const float* feats  = (const float*)d_in[1];   // [B,C,N] f32
  // out_size = B*M*3 + B*M*C = M * B * (3+C)
  int M = out_size / (BB * (3 + CC));            // = 2048
  if (M <= 0) M = 1;

  float* out_pts = (float*)d_out;                        // [B,M,3]
  float* out_f   = (float*)d_out + (size_t)BB * M * 3;   // [B,M,C]

  int* idx_ws = (int*)d_ws;                              // B*M ints
  size_t idx_bytes = (((size_t)BB * M * sizeof(int)) + 255) & ~(size_t)255;
  size_t trans_bytes = (size_t)BB * NN * CC * sizeof(float);   // 134.2 MB
  bool use_t = (ws_size >= idx_bytes + trans_bytes);
  float* trans = (float*)((char*)d_ws + idx_bytes);

  int grid = use_t ? (BB + TBLOCKS) : BB;
  fps_fused_kernel<<<dim3(grid), dim3(NT), 0, stream>>>(
      points, feats, out_pts, idx_ws, trans, M, use_t ? 1 : 0);

  if (use_t) {
    gather_t_kernel<<<dim3((BB * M + 3) / 4), dim3(256), 0, stream>>>(
        trans, idx_ws, out_f, M);
  } else {
    gather_kernel<<<dim3(BB * M), dim3(CC), 0, stream>>>(feats, idx_ws, out_f, M);
  }
}

// Round 4
// 2027.316 us; speedup vs baseline: 1.0781x; 1.0781x over previous
//
#include <hip/hip_runtime.h>
#include <cfloat>

// Problem constants: B=16, N=8192, C=256; M derived from out_size (=2048).
// R4: barrier-locked loop => iter time = fixed per-SIMD issue + tail latency
// + barrier convergence (measured to scale with #waves: 16w=2390cyc/iter,
// 8w=2060). Go DOWN: NT 256 (4 waves), PPT 32. Per-SIMD compute issue is
// unchanged (same total work / 4 SIMDs); tail shortens (4 keys -> 2 DPP
// steps); barrier convergence cheapens. Everything else == the 1757us R0.
#define BB 16
#define NN 8192
#define CC 256
#define NT 256                  // threads per FPS block (4 waves)
#define PPT 32                  // points per thread
#define NPAIR (PPT / 2)         // 16 packed f32x2 pairs
#define NWAVES (NT / 64)        // 4
#define TIT (1024 / NT)         // transpose float4 iters per 64x64 tile (=4)
#define TBLOCKS 240             // transpose helper blocks (fill idle CUs)
#define NTILES (BB * (CC / 64) * (NN / 64))   // 16*4*128 = 8192 64x64 tiles

typedef float    v2f __attribute__((ext_vector_type(2)));
typedef unsigned v2u __attribute__((ext_vector_type(2)));
typedef unsigned uu;
typedef unsigned long long ull;

// Barrier that waits ONLY on LDS (lgkmcnt), not vmcnt. __syncthreads emits
// "s_waitcnt vmcnt(0) lgkmcnt(0); s_barrier" — the vmcnt(0) forces wave 0 to
// wait for its per-iteration global stores (idx/out_pts) to RETIRE before the
// barrier. Our only cross-wave data is the LDS key write -> lgkmcnt(0)
// suffices; global stores are drained at s_endpgm.
#define LDS_BARRIER() __asm__ __volatile__("s_waitcnt lgkmcnt(0)\n\ts_barrier" ::: "memory")

// Shared memory. FPS view: separate x/y/z coord arrays -> winner-coord fetch
// is 3x b32 same-address broadcast (conflict-free). Union with the transpose
// tile so both paths fit one ~98.5 KB block (1 block/CU each).
// NOTE (R0 measured): SQ_LDS_BANK_CONFLICT == 2^21 comes from the transpose
// tile's 2-way aliasing (benign per m136), NOT from the FPS path.
struct SmemFPS {
  float px[NN], py[NN], pz[NN];           // 96 KB point mirror
  ull   key[2][NWAVES];                   // double-buffered wave keys
  float red[NWAVES][3];
  float ctr[3];
};
struct SmemT {
  float tile[64][65];                     // padded transpose tile
};
union Smem { SmemFPS f; SmemT t; };

// ---- guaranteed-packed f32 math (VOP3P). Each half is a plain IEEE f32 op
// (round-to-nearest-even), bit-identical to the scalar version. ----
__device__ __forceinline__ v2f pk_sub(v2f a, v2f b) {
  v2f d;
  asm("v_pk_add_f32 %0, %1, %2 neg_lo:[0,1] neg_hi:[0,1]"
      : "=v"(d) : "v"(a), "v"(b));
  return d;
}
__device__ __forceinline__ v2f pk_mul(v2f a, v2f b) {
  v2f d;
  asm("v_pk_mul_f32 %0, %1, %2" : "=v"(d) : "v"(a), "v"(b));
  return d;
}
__device__ __forceinline__ v2f pk_add(v2f a, v2f b) {
  v2f d;
  asm("v_pk_add_f32 %0, %1, %2" : "=v"(d) : "v"(a), "v"(b));
  return d;
}

__device__ __forceinline__ uu umin2(uu a, uu b) { return a < b ? a : b; }
__device__ __forceinline__ uu umax2(uu a, uu b) { return a > b ? a : b; }

// key = (dist_bits << 32) | ~index. dist >= 0 -> u32 bit order == f32 order.
// max key = max dist; tie -> larger ~idx = smaller idx = numpy first-occurrence.
__device__ __forceinline__ ull max64(ull a, ull b) { return a > b ? a : b; }

// One DPP max step on a u64 key (both 32-bit halves move with same pattern).
template <int CTRL>
__device__ __forceinline__ ull dpp_max64(ull x) {
  int lo = (int)(uu)x;
  int hi = (int)(uu)(x >> 32);
  int plo = __builtin_amdgcn_update_dpp(0, lo, CTRL, 0xF, 0xF, true);
  int phi = __builtin_amdgcn_update_dpp(0, hi, CTRL, 0xF, 0xF, true);
  ull p = ((ull)(uu)phi << 32) | (uu)plo;
  return max64(x, p);
}

// Wave64 max funneled into lane 63, all on the VALU pipe (no LDS-pipe ops).
__device__ __forceinline__ ull wave_max63(ull k) {
  k = dpp_max64<0xB1>(k);    // quad_perm xor1
  k = dpp_max64<0x4E>(k);    // quad_perm xor2
  k = dpp_max64<0x124>(k);   // row_ror:4
  k = dpp_max64<0x128>(k);   // row_ror:8 -> full 16-lane row max
  k = dpp_max64<0x142>(k);   // row_bcast15
  k = dpp_max64<0x143>(k);   // row_bcast31 -> lane 63 has wave max
  return k;
}

// blockIdx < BB: one FPS workgroup per batch.
// blockIdx >= BB (when do_trans): grid-stride transpose of features
// [B][C][N] -> trans [B][N][C], hidden under FPS on the idle 240 CUs.
__global__ __launch_bounds__(NT)
void fps_fused_kernel(const float* __restrict__ pts,
                      const float* __restrict__ feats,
                      float* __restrict__ out_pts,
                      int* __restrict__ idx_out,
                      float* __restrict__ trans, int M, int do_trans) {
  __shared__ Smem sm;
  const int t = threadIdx.x;

  if (blockIdx.x >= BB) {
    // ---------------- transpose path ----------------
    if (!do_trans) return;
    for (int tileId = blockIdx.x - BB; tileId < NTILES; tileId += TBLOCKS) {
      int b  = tileId / ((CC / 64) * (NN / 64));
      int r  = tileId % ((CC / 64) * (NN / 64));
      int ct = r / (NN / 64);           // c-tile 0..3
      int nt = r % (NN / 64);           // n-tile 0..127
      const float* src = feats + ((size_t)b * CC + ct * 64) * NN + nt * 64;
      float* dst = trans + ((size_t)b * NN + nt * 64) * CC + ct * 64;
#pragma unroll
      for (int i = 0; i < TIT; ++i) {   // 1024 float4 loads total per tile
        int f = t + i * NT;             // f in [0,1024)
        int c = f >> 4, n4 = f & 15;
        float4 v = *(const float4*)(src + (size_t)c * NN + n4 * 4);
        sm.t.tile[c][n4 * 4 + 0] = v.x;
        sm.t.tile[c][n4 * 4 + 1] = v.y;
        sm.t.tile[c][n4 * 4 + 2] = v.z;
        sm.t.tile[c][n4 * 4 + 3] = v.w;
      }
      __syncthreads();
#pragma unroll
      for (int i = 0; i < TIT; ++i) {
        int f = t + i * NT;
        int n = f >> 4, c4 = f & 15;
        float4 o;
        o.x = sm.t.tile[c4 * 4 + 0][n];
        o.y = sm.t.tile[c4 * 4 + 1][n];
        o.z = sm.t.tile[c4 * 4 + 2][n];
        o.w = sm.t.tile[c4 * 4 + 3][n];
        *(float4*)(dst + (size_t)n * CC + c4 * 4) = o;
      }
      __syncthreads();                  // tile reuse across grid-stride iters
    }
    return;
  }

  // ---------------- FPS path ----------------
  const int b = blockIdx.x;
  const int wave = t >> 6;
  const int lane = t & 63;
  const float* base = pts + (size_t)b * 3 * NN;   // [3][N] for this batch

  v2f px2[NPAIR], py2[NPAIR], pz2[NPAIR];
  v2u dist2[NPAIR];
  const uu INIT = __float_as_uint(1e10f);         // matches jnp.full(1e10)
#pragma unroll
  for (int j = 0; j < NPAIR; ++j) {
    int n0 = t + (2 * j) * NT;                    // coalesced loads
    int n1 = t + (2 * j + 1) * NT;
    float x0 = base[n0], y0 = base[NN + n0], z0 = base[2 * NN + n0];
    float x1 = base[n1], y1 = base[NN + n1], z1 = base[2 * NN + n1];
    px2[j] = (v2f){x0, x1};
    py2[j] = (v2f){y0, y1};
    pz2[j] = (v2f){z0, z1};
    sm.f.px[n0] = x0; sm.f.py[n0] = y0; sm.f.pz[n0] = z0;
    sm.f.px[n1] = x1; sm.f.py[n1] = y1; sm.f.pz[n1] = z1;
    dist2[j] = (v2u){INIT, INIT};
  }

  // ---- centroid (one-time; latency irrelevant; standard barriers OK) ----
  float sx = 0.f, sy = 0.f, sz = 0.f;
#pragma unroll
  for (int j = 0; j < NPAIR; ++j) {
    sx += px2[j].x; sx += px2[j].y;
    sy += py2[j].x; sy += py2[j].y;
    sz += pz2[j].x; sz += pz2[j].y;
  }
#pragma unroll
  for (int off = 32; off > 0; off >>= 1) {
    sx += __shfl_xor(sx, off);
    sy += __shfl_xor(sy, off);
    sz += __shfl_xor(sz, off);
  }
  if (lane == 0) { sm.f.red[wave][0] = sx; sm.f.red[wave][1] = sy; sm.f.red[wave][2] = sz; }
  __syncthreads();    // also covers coord-mirror staging writes
  if (t == 0) {
    float gx = 0.f, gy = 0.f, gz = 0.f;
    for (int w = 0; w < NWAVES; ++w) { gx += sm.f.red[w][0]; gy += sm.f.red[w][1]; gz += sm.f.red[w][2]; }
    sm.f.ctr[0] = gx / NN; sm.f.ctr[1] = gy / NN; sm.f.ctr[2] = gz / NN;  // /8192 exact
  }
  __syncthreads();
  const float ctx = sm.f.ctr[0], cty = sm.f.ctr[1], ctz = sm.f.ctr[2];

  int ep = 0;   // key epoch (parity double-buffer -> one barrier per iter)
  int ci;

  // Tail: u64 key wave reduce via DPP (VALU only), lane-63 write, ONE
  // lgkm-only barrier, then a spread b64 read (lane reads key[lane&3];
  // 4 distinct addresses spanning 32B -> conflict-free broadcast groups)
  // + 2 DPP steps so every lane holds the block max over the 4 wave keys.
  auto reduce_tail = [&](uu v, int bk) {
    ull key = ((ull)v << 32) | (uu)(~(uu)(t + bk * NT));
    key = wave_max63(key);
    ep ^= 1;
    if (lane == 63) sm.f.key[ep][wave] = key;
    LDS_BARRIER();                      // lgkmcnt-only: no global-store drain
    ull kk = sm.f.key[ep][lane & 3];    // spread ds_read_b64
    kk = dpp_max64<0xB1>(kk);           // xor1 within 4-key group
    kk = dpp_max64<0x4E>(kk);           // xor2 -> completes all-4 max
    ci = (int)~(uu)kk;
  };

  // ---- initial farthest = argmax of dist-to-centroid (no dist update) ----
  {
    v2f c2x = {ctx, ctx}, c2y = {cty, cty}, c2z = {ctz, ctz};
    v2u nd2[NPAIR];
    uu v = 0u;
#pragma unroll
    for (int j = 0; j < NPAIR; ++j) {
      v2f dx = pk_sub(px2[j], c2x);
      v2f dy = pk_sub(py2[j], c2y);
      v2f dz = pk_sub(pz2[j], c2z);
      // exact numpy order: ((dx*dx + dy*dy) + dz*dz), no FMA
      v2f d = pk_add(pk_add(pk_mul(dx, dx), pk_mul(dy, dy)), pk_mul(dz, dz));
      v2u du = (v2u){__float_as_uint(d.x), __float_as_uint(d.y)};
      nd2[j] = du;
      v = umax2(v, umax2(du.x, du.y));           // v_max3_u32
    }
    int bk = 0;
#pragma unroll
    for (int k = PPT - 1; k >= 0; --k) {         // descending: keeps smallest k
      uu ndk = (k & 1) ? nd2[k >> 1].y : nd2[k >> 1].x;
      if (ndk == v) bk = k;                      // first-occurrence tie-break
    }
    reduce_tail(v, bk);
  }

  // ---- FPS main loop ----
  for (int m = 0; m < M; ++m) {
    // winner coords: 3x b32 same-address broadcast (conflict-free)
    float cx = sm.f.px[ci], cy = sm.f.py[ci], cz = sm.f.pz[ci];
    if (t == 0) {
      idx_out[b * M + m] = ci;
      size_t o = ((size_t)b * M + m) * 3;
      out_pts[o] = cx; out_pts[o + 1] = cy; out_pts[o + 2] = cz;
    }
    if (m == M - 1) break;

    v2f c2x = {cx, cx}, c2y = {cy, cy}, c2z = {cz, cz};
    uu v = 0u;
#pragma unroll
    for (int j = 0; j < NPAIR; ++j) {
      v2f dx = pk_sub(px2[j], c2x);
      v2f dy = pk_sub(py2[j], c2y);
      v2f dz = pk_sub(pz2[j], c2z);
      v2f d = pk_add(pk_add(pk_mul(dx, dx), pk_mul(dy, dy)), pk_mul(dz, dz));
      // dists >= 0 -> u32 min/max on the bits == f32 min/max
      v2u nd;
      nd.x = umin2(dist2[j].x, __float_as_uint(d.x));
      nd.y = umin2(dist2[j].y, __float_as_uint(d.y));
      dist2[j] = nd;                     // updated in place; tie-break reads it
      v = umax2(v, umax2(nd.x, nd.y));   // v_max3_u32 chain
    }
    int bk = 0;
#pragma unroll
    for (int k = PPT - 1; k >= 0; --k) {
      uu ndk = (k & 1) ? dist2[k >> 1].y : dist2[k >> 1].x;
      if (ndk == v) bk = k;
    }
    reduce_tail(v, bk);
  }
}

// Gather from transposed features: fully coalesced float4 both sides.
__global__ __launch_bounds__(256)
void gather_t_kernel(const float* __restrict__ trans,
                     const int* __restrict__ idx,
                     float* __restrict__ out_f, int M) {
  int gm = blockIdx.x * 4 + (threadIdx.x >> 6);
  if (gm >= BB * M) return;
  int lane = threadIdx.x & 63;
  int b = gm / M;
  int n = idx[gm];
  float4 v = *(const float4*)(trans + ((size_t)b * NN + n) * CC + lane * 4);
  *(float4*)(out_f + (size_t)gm * CC + lane * 4) = v;
}

// Fallback gather (ws too small for transpose): scattered reads, L2/L3-bound.
__global__ __launch_bounds__(CC)
void gather_kernel(const float* __restrict__ feats, const int* __restrict__ idx,
                   float* __restrict__ out_f, int M) {
  const int bm = blockIdx.x;
  const int b = bm / M;
  const int n = idx[bm];
  const int c = threadIdx.x;
  out_f[(size_t)bm * CC + c] = feats[((size_t)b * CC + c) * NN + n];
}

extern "C" void kernel_launch(void* const* d_in, const int* in_sizes, int n_in,
                              void* d_out, int out_size, void* d_ws, size_t ws_size,
                              hipStream_t stream) {
  const float* points = (const float*)d_in[0];   // [B,3,N] f32
  const float* feats  = (const float*)d_in[1];   // [B,C,N] f32
  // out_size = B*M*3 + B*M*C = M * B * (3+C)
  int M = out_size / (BB * (3 + CC));            // = 2048
  if (M <= 0) M = 1;

  float* out_pts = (float*)d_out;                        // [B,M,3]
  float* out_f   = (float*)d_out + (size_t)BB * M * 3;   // [B,M,C]

  int* idx_ws = (int*)d_ws;                              // B*M ints
  size_t idx_bytes = (((size_t)BB * M * sizeof(int)) + 255) & ~(size_t)255;
  size_t trans_bytes = (size_t)BB * NN * CC * sizeof(float);   // 134.2 MB
  bool use_t = (ws_size >= idx_bytes + trans_bytes);
  float* trans = (float*)((char*)d_ws + idx_bytes);

  int grid = use_t ? (BB + TBLOCKS) : BB;
  fps_fused_kernel<<<dim3(grid), dim3(NT), 0, stream>>>(
      points, feats, out_pts, idx_ws, trans, M, use_t ? 1 : 0);

  if (use_t) {
    gather_t_kernel<<<dim3((BB * M + 3) / 4), dim3(256), 0, stream>>>(
        trans, idx_ws, out_f, M);
  } else {
    gather_kernel<<<dim3(BB * M), dim3(CC), 0, stream>>>(feats, idx_ws, out_f, M);
  }
}